// Round 12
// baseline (2101.683 us; speedup 1.0000x reference)
//
#include <hip/hip_runtime.h>

#define N_NODES 4096
#define H_DIM 32
#define F_INPUT 5
#define ROLLS 200
#define NBLK 256
#define NBUF 64                          // Mt ring: write-once per 64 steps
#define MT_ELEMS ((size_t)H_DIM * N_NODES)   // 131072 shorts = 256 KiB

typedef __attribute__((ext_vector_type(8))) short bf16x8;
typedef __attribute__((ext_vector_type(4))) float fx4;

__device__ __forceinline__ unsigned short f2bf(float f) {
  unsigned int u = __builtin_bit_cast(unsigned int, f);
  u += 0x7fffu + ((u >> 16) & 1u);   // round-to-nearest-even (inputs are benign, no NaN/inf)
  return (unsigned short)(u >> 16);
}

// Single-poller barrier: wave 0 polls all 256 block flags (4/lane,
// agent-scope = L2-bypassing loads); waves 1-7 park at the syncthreads.
// Flags are bumped +1 by each of the two publisher waves -> target 2*(t+1).
__device__ __forceinline__ void wait_all(const unsigned* flags, int tid,
                                         unsigned target) {
  if (tid < 64) {
    for (;;) {
      bool ok = true;
#pragma unroll
      for (int j = 0; j < 4; ++j) {
        unsigned v = __hip_atomic_load(&flags[tid * 4 + j], __ATOMIC_RELAXED,
                                       __HIP_MEMORY_SCOPE_AGENT);
        ok = ok && (v >= target);
      }
      if (__ballot(ok) == ~0ull) break;
      __builtin_amdgcn_s_sleep(1);
    }
  }
  __syncthreads();
  asm volatile("" ::: "memory");   // keep Mt loads below the wait
}

// Persistent cooperative kernel (r11 structure, tail collapsed to 4 barriers).
// grid = 256 blocks (1/CU), 512 threads (8 waves), 16 rows/block. A in
// VGPRs; h in LDS; c in a register per thread; Mt ring (64) in global,
// block-major slot layout (shorts): slot[bid*512 + h*16 + row].
// Publish: waves 0,1 store their Mnext half DIRECT from registers as one
// contiguous 512 B burst each, then each bumps flags[bid] by +1.
__global__ __launch_bounds__(512, 2) void k_roll(
    const float* __restrict__ A, const float* __restrict__ X,
    const float* __restrict__ Wx, const float* __restrict__ Wh, const float* __restrict__ Wc,
    const float* __restrict__ Wih, const float* __restrict__ Whh,
    const float* __restrict__ b_ih, const float* __restrict__ b_hh,
    const float* __restrict__ Wfc, const float* __restrict__ b_fc,
    float* __restrict__ out,
    unsigned short* __restrict__ bufs, unsigned* __restrict__ flags) {

  __shared__ __align__(16) float red[8 * 16 * 36];          // pad 36: 16B-aligned rows
  __shared__ __align__(16) unsigned short hB[16 * 48];      // persistent h (bf16 frag)
  __shared__ __align__(16) unsigned short cnB[16 * 48];     // c_new bf16 (M_next A-op)
  __shared__ __align__(16) float gatesLds[16 * 132];
  __shared__ __align__(16) float xLds[16 * 8];

  const int tid  = threadIdx.x;
  const int wave = tid >> 6;        // 0..7
  const int lane = tid & 63;
  const int l15  = lane & 15;
  const int quad = lane >> 4;       // 0..3
  const int bid  = blockIdx.x;
  const int row0 = bid << 4;

  // ---- prologue: A fragments fp32->bf16 into VGPRs (once) ----
  bf16x8 areg[16];
  {
    const float* Ap = A + (size_t)(row0 + l15) * N_NODES + wave * 512 + quad * 8;
#pragma unroll
    for (int kk = 0; kk < 16; ++kk) {
      bf16x8 a;
#pragma unroll
      for (int j = 0; j < 8; ++j) a[j] = (short)f2bf(Ap[kk * 32 + j]);
      areg[kk] = a;
    }
  }

  // gate weight fragments: wave w owns gate cols [16w, 16w+16)
  const int g = (wave << 4) + l15;
  bf16x8 bI, bH;
#pragma unroll
  for (int j = 0; j < 8; ++j) {
    bI[j] = (short)f2bf(Wih[g * 32 + quad * 8 + j]);
    bH[j] = (short)f2bf(Whh[g * 32 + quad * 8 + j]);
  }
  const float bias = b_ih[g] + b_hh[g];

  // M_next weight fragments (waves 0,1 only): WhT[n][k]=Wh[k][n]; n = g
  bf16x8 bWh, bWc;
  float wx5[F_INPUT];
  if (wave < 2) {
#pragma unroll
    for (int j = 0; j < 8; ++j) {
      bWh[j] = (short)f2bf(Wh[(quad * 8 + j) * H_DIM + g]);
      bWc[j] = (short)f2bf(Wc[(quad * 8 + j) * H_DIM + g]);
    }
#pragma unroll
    for (int f = 0; f < F_INPUT; ++f) wx5[f] = Wx[f * H_DIM + g];
  }

  float c_reg = 0.f;                 // thread (tid>>5, tid&31) owns one cell

  // init: h0 = 0; Mt0 = (x0 @ Wx)^T staged as floats in gatesLds
  for (int i = tid; i < 16 * 48; i += 512) hB[i] = 0;   // f2bf(0)==0
  {
    int r = tid >> 5, k = tid & 31;
    float s = 0.f;
#pragma unroll
    for (int f = 0; f < F_INPUT; ++f)
      s += X[(size_t)(row0 + r) * F_INPUT + f] * Wx[f * H_DIM + k];
    gatesLds[r * 132 + k] = s;
  }
  __syncthreads();
  if (wave < 2) {                    // publish Mt0: 512 B burst per wave, +1 flag
    unsigned short us[4];
#pragma unroll
    for (int r = 0; r < 4; ++r)
      us[r] = f2bf(gatesLds[(quad * 4 + r) * 132 + g]);
    unsigned long long v = (unsigned long long)(us[0] | ((unsigned)us[1] << 16))
                         | ((unsigned long long)(us[2] | ((unsigned)us[3] << 16)) << 32);
    char* slot = (char*)(bufs + (size_t)bid * 512);
    __hip_atomic_store((unsigned long long*)(slot + g * 32 + quad * 8), v,
                       __ATOMIC_RELAXED, __HIP_MEMORY_SCOPE_AGENT);
    asm volatile("s_waitcnt vmcnt(0)" ::: "memory");
    if (lane == 0)
      __hip_atomic_fetch_add(&flags[bid], 1u, __ATOMIC_RELAXED,
                             __HIP_MEMORY_SCOPE_AGENT);
  }

  for (int t = 0; t < ROLLS; ++t) {
    const unsigned short* m0 = bufs + (size_t)(t & (NBUF - 1)) * MT_ELEMS;
    unsigned short* m1 = bufs + (size_t)((t + 1) & (NBUF - 1)) * MT_ELEMS;

    // ring wrap (t = 0,64,128,192): one L1/L2 tag-invalidate before reuse
    if ((t & (NBUF - 1)) == 0) {
      __syncthreads();
      if (tid < 64)
        __builtin_amdgcn_fence(__ATOMIC_ACQUIRE, "agent");
      __syncthreads();
    }

    // barrier #1: wave 0 polls all 256 flags; others park at syncthreads
    wait_all(flags, tid, 2u * (unsigned)(t + 1));

    // stage x_{t+1} early (waves 0,1 write; same waves read in phase E)
    if (t + 1 < ROLLS && tid < 128) {
      int r = tid >> 3, f = tid & 7;
      if (f < F_INPUT)
        xLds[r * 8 + f] = X[(size_t)(t + 1) * N_NODES * F_INPUT +
                            (size_t)(row0 + r) * F_INPUT + f];
    }

    // ---- phase A: all 32 Mt loads issued first, then MFMA chain ----
    fx4 acc0 = {0.f, 0.f, 0.f, 0.f}, acc1 = {0.f, 0.f, 0.f, 0.f};
    {
      const unsigned short* Bb = m0 + ((wave << 5) + (quad >> 1)) * 512
                                    + l15 * 16 + (quad & 1) * 8;
      bf16x8 b0s[16], b1s[16];
#pragma unroll
      for (int s = 0; s < 16; ++s) {
        b0s[s] = *(const bf16x8*)(Bb + s * 1024);
        b1s[s] = *(const bf16x8*)(Bb + s * 1024 + 256);
      }
      __builtin_amdgcn_sched_barrier(0);   // keep all loads issued first
#pragma unroll
      for (int s = 0; s < 16; ++s) {
        acc0 = __builtin_amdgcn_mfma_f32_16x16x32_bf16(areg[s], b0s[s], acc0, 0, 0, 0);
        acc1 = __builtin_amdgcn_mfma_f32_16x16x32_bf16(areg[s], b1s[s], acc1, 0, 0, 0);
      }
    }
#pragma unroll
    for (int r = 0; r < 4; ++r) {
      red[(wave * 16 + quad * 4 + r) * 36 + l15]      = acc0[r];
      red[(wave * 16 + quad * 4 + r) * 36 + 16 + l15] = acc1[r];
    }
    __syncthreads();                       // barrier #2: red complete

    // ---- fused B+C: every wave reduces its own aI fragment from red
    // (same w-order as the old phase B -> bit-identical bf16), then gates.
    {
      fx4 sum0 = {0.f, 0.f, 0.f, 0.f}, sum1 = {0.f, 0.f, 0.f, 0.f};
#pragma unroll
      for (int w = 0; w < 8; ++w) {
        const fx4* p = (const fx4*)&red[((w << 4) + l15) * 36 + quad * 8];
        sum0 += p[0];
        sum1 += p[1];
      }
      bf16x8 aI;
#pragma unroll
      for (int j = 0; j < 4; ++j) {
        aI[j]     = (short)f2bf(sum0[j]);
        aI[4 + j] = (short)f2bf(sum1[j]);
      }
      bf16x8 aH = *(const bf16x8*)(hB + l15 * 48 + quad * 8);
      fx4 gacc = {0.f, 0.f, 0.f, 0.f};
      gacc = __builtin_amdgcn_mfma_f32_16x16x32_bf16(aI, bI, gacc, 0, 0, 0);
      gacc = __builtin_amdgcn_mfma_f32_16x16x32_bf16(aH, bH, gacc, 0, 0, 0);
#pragma unroll
      for (int r = 0; r < 4; ++r) gatesLds[(quad * 4 + r) * 132 + g] = gacc[r] + bias;
    }
    __syncthreads();                       // barrier #3: gates complete

    // ---- phase D: LSTM cell elementwise (c in register) ----
    {
      int r = tid >> 5, k = tid & 31;
      float gi = gatesLds[r * 132 + k];
      float gf = gatesLds[r * 132 + 32 + k];
      float gg = gatesLds[r * 132 + 64 + k];
      float go = gatesLds[r * 132 + 96 + k];
      float i_ = 1.f / (1.f + __expf(-gi));
      float f_ = 1.f / (1.f + __expf(-gf));
      float g_ = tanhf(gg);
      float o_ = 1.f / (1.f + __expf(-go));
      float cn = f_ * c_reg + i_ * g_;
      float hn = o_ * tanhf(cn);
      c_reg = cn;
      hB[r * 48 + k]  = f2bf(hn);          // next step's h fragment
      cnB[r * 48 + k] = f2bf(cn);
      if (t == ROLLS - 1) gatesLds[r * 132 + k] = hn * Wfc[k];
    }
    __syncthreads();                       // barrier #4: h/c tiles complete

    // ---- phase E + publish (waves 0,1): Mnext from registers, direct
    // 512 B agent-store burst per wave, own drain, +1 flag each ----
    if (t < ROLLS - 1 && wave < 2) {
      bf16x8 aHn = *(const bf16x8*)(hB  + l15 * 48 + quad * 8);
      bf16x8 aCn = *(const bf16x8*)(cnB + l15 * 48 + quad * 8);
      fx4 m4 = {0.f, 0.f, 0.f, 0.f};
      m4 = __builtin_amdgcn_mfma_f32_16x16x32_bf16(aHn, bWh, m4, 0, 0, 0);
      m4 = __builtin_amdgcn_mfma_f32_16x16x32_bf16(aCn, bWc, m4, 0, 0, 0);
      unsigned short us[4];
#pragma unroll
      for (int r = 0; r < 4; ++r) {
        float xs = m4[r];
#pragma unroll
        for (int f = 0; f < F_INPUT; ++f)
          xs += xLds[(quad * 4 + r) * 8 + f] * wx5[f];
        us[r] = f2bf(xs);
      }
      unsigned long long v = (unsigned long long)(us[0] | ((unsigned)us[1] << 16))
                           | ((unsigned long long)(us[2] | ((unsigned)us[3] << 16)) << 32);
      char* slot = (char*)(m1 + (size_t)bid * 512);
      __hip_atomic_store((unsigned long long*)(slot + g * 32 + quad * 8), v,
                         __ATOMIC_RELAXED, __HIP_MEMORY_SCOPE_AGENT);
      asm volatile("s_waitcnt vmcnt(0)" ::: "memory");
      if (lane == 0)
        __hip_atomic_fetch_add(&flags[bid], 1u, __ATOMIC_RELAXED,
                               __HIP_MEMORY_SCOPE_AGENT);
    }
  }

  // ---- epilogue: out = h_final @ Wfc^T + b_fc ----
  __syncthreads();
  if (tid < 16) {
    float s = b_fc[0];
#pragma unroll
    for (int k = 0; k < 32; ++k) s += gatesLds[tid * 132 + k];
    out[row0 + tid] = s;
  }
}

extern "C" void kernel_launch(void* const* d_in, const int* in_sizes, int n_in,
                              void* d_out, int out_size, void* d_ws, size_t ws_size,
                              hipStream_t stream) {
  (void)in_sizes; (void)n_in; (void)out_size; (void)ws_size;
  const float* X   = (const float*)d_in[0];
  const float* A   = (const float*)d_in[1];
  const float* Wx  = (const float*)d_in[2];
  const float* Wh  = (const float*)d_in[3];
  const float* Wc  = (const float*)d_in[4];
  const float* Wih = (const float*)d_in[5];
  const float* Whh = (const float*)d_in[6];
  const float* bih = (const float*)d_in[7];
  const float* bhh = (const float*)d_in[8];
  const float* Wfc = (const float*)d_in[9];
  const float* bfc = (const float*)d_in[10];
  float* outp = (float*)d_out;

  char* ws = (char*)d_ws;
  unsigned short* bufs = (unsigned short*)ws;
  ws += (size_t)NBUF * MT_ELEMS * 2;           // 16 MiB Mt ring
  unsigned* flags = (unsigned*)ws;
  ws += NBLK * sizeof(unsigned);

  // epoch flags must start at 0 every call (graph-capturable async memset)
  (void)hipMemsetAsync(flags, 0, NBLK * sizeof(unsigned), stream);

  void* args[] = {
    (void*)&A, (void*)&X, (void*)&Wx, (void*)&Wh, (void*)&Wc,
    (void*)&Wih, (void*)&Whh, (void*)&bih, (void*)&bhh,
    (void*)&Wfc, (void*)&bfc, (void*)&outp,
    (void*)&bufs, (void*)&flags
  };
  (void)hipLaunchCooperativeKernel((const void*)k_roll, dim3(NBLK), dim3(512),
                                   args, 0, stream);
}

// Round 13
// 1934.018 us; speedup vs baseline: 1.0867x; 1.0867x over previous
//
#include <hip/hip_runtime.h>

#define N_NODES 4096
#define H_DIM 32
#define F_INPUT 5
#define ROLLS 200
#define NBLK 256
#define NBUF 64                          // Mt ring: write-once per 64 steps
#define MT_ELEMS ((size_t)H_DIM * N_NODES)   // 131072 shorts = 256 KiB

typedef __attribute__((ext_vector_type(8))) short bf16x8;
typedef __attribute__((ext_vector_type(4))) float fx4;

__device__ __forceinline__ unsigned short f2bf(float f) {
  unsigned int u = __builtin_bit_cast(unsigned int, f);
  u += 0x7fffu + ((u >> 16) & 1u);   // round-to-nearest-even (inputs are benign, no NaN/inf)
  return (unsigned short)(u >> 16);
}

// Single-poller barrier: wave 0 polls all 256 block flags (4/lane,
// agent-scope = L2-bypassing loads); waves 1-7 park at the syncthreads.
// Flags are bumped +1 by each of the two publisher waves -> target 2*(t+1).
__device__ __forceinline__ void wait_all(const unsigned* flags, int tid,
                                         unsigned target) {
  if (tid < 64) {
    for (;;) {
      bool ok = true;
#pragma unroll
      for (int j = 0; j < 4; ++j) {
        unsigned v = __hip_atomic_load(&flags[tid * 4 + j], __ATOMIC_RELAXED,
                                       __HIP_MEMORY_SCOPE_AGENT);
        ok = ok && (v >= target);
      }
      if (__ballot(ok) == ~0ull) break;
      __builtin_amdgcn_s_sleep(1);
    }
  }
  __syncthreads();
  asm volatile("" ::: "memory");   // keep Mt loads below the wait
}

// Persistent cooperative kernel (r11 structure + direct-register publish).
// grid = 256 blocks (1/CU), 512 threads (8 waves), 16 rows/block. A in
// VGPRs; h/c in LDS; Mt ring (64) in global, block-major slot layout
// (shorts): slot[bid*512 + h*16 + row].
// Publish: waves 0,1 store their Mnext half DIRECT from registers as one
// contiguous 512 B burst each (full lines), then each bumps flags[bid] +1.
__global__ __launch_bounds__(512, 2) void k_roll(
    const float* __restrict__ A, const float* __restrict__ X,
    const float* __restrict__ Wx, const float* __restrict__ Wh, const float* __restrict__ Wc,
    const float* __restrict__ Wih, const float* __restrict__ Whh,
    const float* __restrict__ b_ih, const float* __restrict__ b_hh,
    const float* __restrict__ Wfc, const float* __restrict__ b_fc,
    float* __restrict__ out,
    unsigned short* __restrict__ bufs, unsigned* __restrict__ flags) {

  __shared__ __align__(16) float red[8 * 16 * 33];          // split-K partials (pad 33)
  __shared__ __align__(16) unsigned short inpB[16 * 48];    // inp bf16, A-frag layout
  __shared__ __align__(16) unsigned short hB[16 * 48];      // persistent h (bf16 frag)
  __shared__ __align__(16) unsigned short cnB[16 * 48];     // c_new bf16 (for M_next)
  __shared__ __align__(16) float cB[16 * 32];               // persistent c (fp32)
  __shared__ __align__(16) float gatesLds[16 * 132];
  __shared__ __align__(16) float xLds[16 * 8];

  const int tid  = threadIdx.x;
  const int wave = tid >> 6;        // 0..7
  const int lane = tid & 63;
  const int l15  = lane & 15;
  const int quad = lane >> 4;       // 0..3
  const int bid  = blockIdx.x;
  const int row0 = bid << 4;

  // ---- prologue: A fragments fp32->bf16 into VGPRs (once) ----
  bf16x8 areg[16];
  {
    const float* Ap = A + (size_t)(row0 + l15) * N_NODES + wave * 512 + quad * 8;
#pragma unroll
    for (int kk = 0; kk < 16; ++kk) {
      bf16x8 a;
#pragma unroll
      for (int j = 0; j < 8; ++j) a[j] = (short)f2bf(Ap[kk * 32 + j]);
      areg[kk] = a;
    }
  }

  // gate weight fragments: wave w owns gate cols [16w, 16w+16)
  const int g = (wave << 4) + l15;
  bf16x8 bI, bH;
#pragma unroll
  for (int j = 0; j < 8; ++j) {
    bI[j] = (short)f2bf(Wih[g * 32 + quad * 8 + j]);
    bH[j] = (short)f2bf(Whh[g * 32 + quad * 8 + j]);
  }
  const float bias = b_ih[g] + b_hh[g];

  // M_next weight fragments (waves 0,1 only): WhT[n][k]=Wh[k][n]; n = g
  bf16x8 bWh, bWc;
  float wx5[F_INPUT];
  if (wave < 2) {
#pragma unroll
    for (int j = 0; j < 8; ++j) {
      bWh[j] = (short)f2bf(Wh[(quad * 8 + j) * H_DIM + g]);
      bWc[j] = (short)f2bf(Wc[(quad * 8 + j) * H_DIM + g]);
    }
#pragma unroll
    for (int f = 0; f < F_INPUT; ++f) wx5[f] = Wx[f * H_DIM + g];
  }

  // h = c = 0 ; Mt0 = (x0 @ Wx)^T staged as floats in gatesLds
  {
    int r = tid >> 5, k = tid & 31;
    hB[r * 48 + k] = 0;       // f2bf(0)==0
    cB[r * 32 + k] = 0.f;
    float s = 0.f;
#pragma unroll
    for (int f = 0; f < F_INPUT; ++f)
      s += X[(size_t)(row0 + r) * F_INPUT + f] * Wx[f * H_DIM + k];
    gatesLds[r * 132 + k] = s;
  }
  __syncthreads();
  if (wave < 2) {              // publish Mt0: 512 B burst per wave, +1 flag each
    unsigned short us[4];
#pragma unroll
    for (int r = 0; r < 4; ++r)
      us[r] = f2bf(gatesLds[(quad * 4 + r) * 132 + g]);
    unsigned long long v = (unsigned long long)(us[0] | ((unsigned)us[1] << 16))
                         | ((unsigned long long)(us[2] | ((unsigned)us[3] << 16)) << 32);
    char* slot = (char*)(bufs + (size_t)bid * 512);
    __hip_atomic_store((unsigned long long*)(slot + g * 32 + quad * 8), v,
                       __ATOMIC_RELAXED, __HIP_MEMORY_SCOPE_AGENT);
    asm volatile("s_waitcnt vmcnt(0)" ::: "memory");
    if (lane == 0)
      __hip_atomic_fetch_add(&flags[bid], 1u, __ATOMIC_RELAXED,
                             __HIP_MEMORY_SCOPE_AGENT);
  }

  for (int t = 0; t < ROLLS; ++t) {
    const unsigned short* m0 = bufs + (size_t)(t & (NBUF - 1)) * MT_ELEMS;
    unsigned short* m1 = bufs + (size_t)((t + 1) & (NBUF - 1)) * MT_ELEMS;

    // ring wrap (t = 0,64,128,192): one L1/L2 tag-invalidate before reuse
    if ((t & (NBUF - 1)) == 0) {
      __syncthreads();
      if (tid < 64)
        __builtin_amdgcn_fence(__ATOMIC_ACQUIRE, "agent");
      __syncthreads();
    }

    // barrier #1: wave 0 polls all 256 flags; others park at syncthreads
    wait_all(flags, tid, 2u * (unsigned)(t + 1));

    // stage x_{t+1} early (waves 0,1 write; same waves read in phase E)
    if (t + 1 < ROLLS && tid < 128) {
      int r = tid >> 3, f = tid & 7;
      if (f < F_INPUT)
        xLds[r * 8 + f] = X[(size_t)(t + 1) * N_NODES * F_INPUT +
                            (size_t)(row0 + r) * F_INPUT + f];
    }

    // ---- phase A: all 32 Mt loads issued first, then MFMA chain ----
    fx4 acc0 = {0.f, 0.f, 0.f, 0.f}, acc1 = {0.f, 0.f, 0.f, 0.f};
    {
      const unsigned short* Bb = m0 + ((wave << 5) + (quad >> 1)) * 512
                                    + l15 * 16 + (quad & 1) * 8;
      bf16x8 b0s[16], b1s[16];
#pragma unroll
      for (int s = 0; s < 16; ++s) {
        b0s[s] = *(const bf16x8*)(Bb + s * 1024);
        b1s[s] = *(const bf16x8*)(Bb + s * 1024 + 256);
      }
      __builtin_amdgcn_sched_barrier(0);   // keep all loads issued first
#pragma unroll
      for (int s = 0; s < 16; ++s) {
        acc0 = __builtin_amdgcn_mfma_f32_16x16x32_bf16(areg[s], b0s[s], acc0, 0, 0, 0);
        acc1 = __builtin_amdgcn_mfma_f32_16x16x32_bf16(areg[s], b1s[s], acc1, 0, 0, 0);
      }
    }
#pragma unroll
    for (int r = 0; r < 4; ++r) {
      red[(wave * 16 + quad * 4 + r) * 33 + l15]      = acc0[r];
      red[(wave * 16 + quad * 4 + r) * 33 + 16 + l15] = acc1[r];
    }
    __syncthreads();                       // barrier #2: red complete

    // ---- phase B: one-pass reduce 8 partials -> inp bf16 ----
    {
      int m = tid >> 5, n = tid & 31;
      float s = 0.f;
#pragma unroll
      for (int w = 0; w < 8; ++w) s += red[(w * 16 + m) * 33 + n];
      inpB[m * 48 + n] = f2bf(s);
    }
    __syncthreads();                       // barrier #3: inpB complete

    // ---- phase C: gates(16x128) = inp@Wih^T + h@Whh^T + b ----
    {
      bf16x8 aI = *(const bf16x8*)(inpB + l15 * 48 + quad * 8);
      bf16x8 aH = *(const bf16x8*)(hB   + l15 * 48 + quad * 8);
      fx4 gacc = {0.f, 0.f, 0.f, 0.f};
      gacc = __builtin_amdgcn_mfma_f32_16x16x32_bf16(aI, bI, gacc, 0, 0, 0);
      gacc = __builtin_amdgcn_mfma_f32_16x16x32_bf16(aH, bH, gacc, 0, 0, 0);
#pragma unroll
      for (int r = 0; r < 4; ++r) gatesLds[(quad * 4 + r) * 132 + g] = gacc[r] + bias;
    }
    __syncthreads();                       // barrier #4: gates complete

    // ---- phase D: LSTM cell elementwise (fp32 state in LDS) ----
    {
      int r = tid >> 5, k = tid & 31;
      float gi = gatesLds[r * 132 + k];
      float gf = gatesLds[r * 132 + 32 + k];
      float gg = gatesLds[r * 132 + 64 + k];
      float go = gatesLds[r * 132 + 96 + k];
      float i_ = 1.f / (1.f + __expf(-gi));
      float f_ = 1.f / (1.f + __expf(-gf));
      float g_ = tanhf(gg);
      float o_ = 1.f / (1.f + __expf(-go));
      float cn = f_ * cB[r * 32 + k] + i_ * g_;
      float hn = o_ * tanhf(cn);
      cB[r * 32 + k] = cn;
      hB[r * 48 + k]  = f2bf(hn);          // next step's h fragment
      cnB[r * 48 + k] = f2bf(cn);
      if (t == ROLLS - 1) gatesLds[r * 132 + k] = hn * Wfc[k];
    }
    __syncthreads();                       // barrier #5: h/c tiles complete

    // ---- phase E + publish (waves 0,1): M_next from registers, one
    // contiguous 512 B agent burst per wave, own drain, +1 flag each ----
    if (t < ROLLS - 1 && wave < 2) {
      bf16x8 aHn = *(const bf16x8*)(hB  + l15 * 48 + quad * 8);
      bf16x8 aCn = *(const bf16x8*)(cnB + l15 * 48 + quad * 8);
      fx4 m4 = {0.f, 0.f, 0.f, 0.f};
      m4 = __builtin_amdgcn_mfma_f32_16x16x32_bf16(aHn, bWh, m4, 0, 0, 0);
      m4 = __builtin_amdgcn_mfma_f32_16x16x32_bf16(aCn, bWc, m4, 0, 0, 0);
      unsigned short us[4];
#pragma unroll
      for (int r = 0; r < 4; ++r) {
        float xs = m4[r];
#pragma unroll
        for (int f = 0; f < F_INPUT; ++f)
          xs += xLds[(quad * 4 + r) * 8 + f] * wx5[f];
        us[r] = f2bf(xs);
      }
      unsigned long long v = (unsigned long long)(us[0] | ((unsigned)us[1] << 16))
                           | ((unsigned long long)(us[2] | ((unsigned)us[3] << 16)) << 32);
      char* slot = (char*)(m1 + (size_t)bid * 512);
      __hip_atomic_store((unsigned long long*)(slot + g * 32 + quad * 8), v,
                         __ATOMIC_RELAXED, __HIP_MEMORY_SCOPE_AGENT);
      asm volatile("s_waitcnt vmcnt(0)" ::: "memory");
      if (lane == 0)
        __hip_atomic_fetch_add(&flags[bid], 1u, __ATOMIC_RELAXED,
                               __HIP_MEMORY_SCOPE_AGENT);
    }
  }

  // ---- epilogue: out = h_final @ Wfc^T + b_fc ----
  __syncthreads();
  if (tid < 16) {
    float s = b_fc[0];
#pragma unroll
    for (int k = 0; k < 32; ++k) s += gatesLds[tid * 132 + k];
    out[row0 + tid] = s;
  }
}

extern "C" void kernel_launch(void* const* d_in, const int* in_sizes, int n_in,
                              void* d_out, int out_size, void* d_ws, size_t ws_size,
                              hipStream_t stream) {
  (void)in_sizes; (void)n_in; (void)out_size; (void)ws_size;
  const float* X   = (const float*)d_in[0];
  const float* A   = (const float*)d_in[1];
  const float* Wx  = (const float*)d_in[2];
  const float* Wh  = (const float*)d_in[3];
  const float* Wc  = (const float*)d_in[4];
  const float* Wih = (const float*)d_in[5];
  const float* Whh = (const float*)d_in[6];
  const float* bih = (const float*)d_in[7];
  const float* bhh = (const float*)d_in[8];
  const float* Wfc = (const float*)d_in[9];
  const float* bfc = (const float*)d_in[10];
  float* outp = (float*)d_out;

  char* ws = (char*)d_ws;
  unsigned short* bufs = (unsigned short*)ws;
  ws += (size_t)NBUF * MT_ELEMS * 2;           // 16 MiB Mt ring
  unsigned* flags = (unsigned*)ws;
  ws += NBLK * sizeof(unsigned);

  // epoch flags must start at 0 every call (graph-capturable async memset)
  (void)hipMemsetAsync(flags, 0, NBLK * sizeof(unsigned), stream);

  void* args[] = {
    (void*)&A, (void*)&X, (void*)&Wx, (void*)&Wh, (void*)&Wc,
    (void*)&Wih, (void*)&Whh, (void*)&bih, (void*)&bhh,
    (void*)&Wfc, (void*)&bfc, (void*)&outp,
    (void*)&bufs, (void*)&flags
  };
  (void)hipLaunchCooperativeKernel((const void*)k_roll, dim3(NBLK), dim3(512),
                                   args, 0, stream);
}

// Round 14
// 1668.517 us; speedup vs baseline: 1.2596x; 1.1591x over previous
//
#include <hip/hip_runtime.h>

#define N_NODES 4096
#define H_DIM 32
#define F_INPUT 5
#define ROLLS 200
#define NBLK 256
#define NBUF 64                          // Mt ring: write-once per 64 steps
#define MT_ELEMS ((size_t)H_DIM * N_NODES)   // 131072 shorts = 256 KiB

typedef __attribute__((ext_vector_type(8))) short bf16x8;
typedef __attribute__((ext_vector_type(4))) float fx4;

__device__ __forceinline__ unsigned short f2bf(float f) {
  unsigned int u = __builtin_bit_cast(unsigned int, f);
  u += 0x7fffu + ((u >> 16) & 1u);   // round-to-nearest-even (inputs are benign, no NaN/inf)
  return (unsigned short)(u >> 16);
}

// Single-poller barrier over TWO plain-store flag arrays (wave0 half /
// wave1 half of each block's Mt slot). 8 pipelined agent loads per lane
// per iteration = one L3 round-trip; waves 1-7 park at the syncthreads.
// NO atomic RMW anywhere (r13's fetch_add contention was -1.2 us/step).
__device__ __forceinline__ void wait_all2(const unsigned* fA,
                                          const unsigned* fB, int tid,
                                          unsigned target) {
  if (tid < 64) {
    for (;;) {
      bool ok = true;
#pragma unroll
      for (int j = 0; j < 4; ++j) {
        unsigned a = __hip_atomic_load(&fA[tid * 4 + j], __ATOMIC_RELAXED,
                                       __HIP_MEMORY_SCOPE_AGENT);
        unsigned b = __hip_atomic_load(&fB[tid * 4 + j], __ATOMIC_RELAXED,
                                       __HIP_MEMORY_SCOPE_AGENT);
        ok = ok && (a >= target) && (b >= target);
      }
      if (__ballot(ok) == ~0ull) break;
      __builtin_amdgcn_s_sleep(1);
    }
  }
  __syncthreads();
  asm volatile("" ::: "memory");   // keep Mt loads below the wait
}

// Persistent cooperative kernel (r11 phases A-D + early register publish).
// grid = 256 blocks (1/CU), 512 threads (8 waves), 16 rows/block. A in
// VGPRs; h/c in LDS; Mt ring (64) in global, block-major slot layout
// (shorts): slot[bid*512 + h*16 + row].
// Publish: waves 0,1 each store their M_next half direct from registers
// (full-line coverage, r13-verified), drain own vmcnt, then PLAIN-store
// their own flag array. No post-E barrier.
__global__ __launch_bounds__(512, 2) void k_roll(
    const float* __restrict__ A, const float* __restrict__ X,
    const float* __restrict__ Wx, const float* __restrict__ Wh, const float* __restrict__ Wc,
    const float* __restrict__ Wih, const float* __restrict__ Whh,
    const float* __restrict__ b_ih, const float* __restrict__ b_hh,
    const float* __restrict__ Wfc, const float* __restrict__ b_fc,
    float* __restrict__ out,
    unsigned short* __restrict__ bufs, unsigned* __restrict__ flagsA,
    unsigned* __restrict__ flagsB) {

  __shared__ __align__(16) float red[8 * 16 * 33];          // split-K partials (pad 33)
  __shared__ __align__(16) unsigned short inpB[16 * 48];    // inp bf16, A-frag layout
  __shared__ __align__(16) unsigned short hB[16 * 48];      // persistent h (bf16 frag)
  __shared__ __align__(16) unsigned short cnB[16 * 48];     // c_new bf16 (for M_next)
  __shared__ __align__(16) float cB[16 * 32];               // persistent c (fp32)
  __shared__ __align__(16) float gatesLds[16 * 132];
  __shared__ __align__(16) float xLds[16 * 8];

  const int tid  = threadIdx.x;
  const int wave = tid >> 6;        // 0..7
  const int lane = tid & 63;
  const int l15  = lane & 15;
  const int quad = lane >> 4;       // 0..3
  const int bid  = blockIdx.x;
  const int row0 = bid << 4;

  // ---- prologue: A fragments fp32->bf16 into VGPRs (once) ----
  bf16x8 areg[16];
  {
    const float* Ap = A + (size_t)(row0 + l15) * N_NODES + wave * 512 + quad * 8;
#pragma unroll
    for (int kk = 0; kk < 16; ++kk) {
      bf16x8 a;
#pragma unroll
      for (int j = 0; j < 8; ++j) a[j] = (short)f2bf(Ap[kk * 32 + j]);
      areg[kk] = a;
    }
  }

  // gate weight fragments: wave w owns gate cols [16w, 16w+16)
  const int g = (wave << 4) + l15;
  bf16x8 bI, bH;
#pragma unroll
  for (int j = 0; j < 8; ++j) {
    bI[j] = (short)f2bf(Wih[g * 32 + quad * 8 + j]);
    bH[j] = (short)f2bf(Whh[g * 32 + quad * 8 + j]);
  }
  const float bias = b_ih[g] + b_hh[g];

  // M_next weight fragments (waves 0,1 only): WhT[n][k]=Wh[k][n]; n = g
  bf16x8 bWh, bWc;
  float wx5[F_INPUT];
  if (wave < 2) {
#pragma unroll
    for (int j = 0; j < 8; ++j) {
      bWh[j] = (short)f2bf(Wh[(quad * 8 + j) * H_DIM + g]);
      bWc[j] = (short)f2bf(Wc[(quad * 8 + j) * H_DIM + g]);
    }
#pragma unroll
    for (int f = 0; f < F_INPUT; ++f) wx5[f] = Wx[f * H_DIM + g];
  }

  // h = c = 0 ; Mt0 = (x0 @ Wx)^T staged as floats in gatesLds
  {
    int r = tid >> 5, k = tid & 31;
    hB[r * 48 + k] = 0;       // f2bf(0)==0
    cB[r * 32 + k] = 0.f;
    float s = 0.f;
#pragma unroll
    for (int f = 0; f < F_INPUT; ++f)
      s += X[(size_t)(row0 + r) * F_INPUT + f] * Wx[f * H_DIM + k];
    gatesLds[r * 132 + k] = s;
  }
  __syncthreads();
  if (wave < 2) {              // publish Mt0 half per wave + own plain flag
    unsigned short us[4];
#pragma unroll
    for (int r = 0; r < 4; ++r)
      us[r] = f2bf(gatesLds[(quad * 4 + r) * 132 + g]);
    unsigned long long v = (unsigned long long)(us[0] | ((unsigned)us[1] << 16))
                         | ((unsigned long long)(us[2] | ((unsigned)us[3] << 16)) << 32);
    char* slot = (char*)(bufs + (size_t)bid * 512);
    __hip_atomic_store((unsigned long long*)(slot + g * 32 + quad * 8), v,
                       __ATOMIC_RELAXED, __HIP_MEMORY_SCOPE_AGENT);
    asm volatile("s_waitcnt vmcnt(0)" ::: "memory");
    if (lane == 0)
      __hip_atomic_store(wave ? &flagsB[bid] : &flagsA[bid], 1u,
                         __ATOMIC_RELAXED, __HIP_MEMORY_SCOPE_AGENT);
  }

  for (int t = 0; t < ROLLS; ++t) {
    const unsigned short* m0 = bufs + (size_t)(t & (NBUF - 1)) * MT_ELEMS;
    unsigned short* m1 = bufs + (size_t)((t + 1) & (NBUF - 1)) * MT_ELEMS;

    // ring wrap (t = 0,64,128,192): one L1/L2 tag-invalidate before reuse
    if ((t & (NBUF - 1)) == 0) {
      __syncthreads();
      if (tid < 64)
        __builtin_amdgcn_fence(__ATOMIC_ACQUIRE, "agent");
      __syncthreads();
    }

    // barrier #1: wave 0 polls both flag arrays; others park at syncthreads
    wait_all2(flagsA, flagsB, tid, (unsigned)(t + 1));

    // stage x_{t+1} early (waves 0,1 write; same waves read in phase E)
    if (t + 1 < ROLLS && tid < 128) {
      int r = tid >> 3, f = tid & 7;
      if (f < F_INPUT)
        xLds[r * 8 + f] = X[(size_t)(t + 1) * N_NODES * F_INPUT +
                            (size_t)(row0 + r) * F_INPUT + f];
    }

    // ---- phase A: all 32 Mt loads issued first, then MFMA chain ----
    fx4 acc0 = {0.f, 0.f, 0.f, 0.f}, acc1 = {0.f, 0.f, 0.f, 0.f};
    {
      const unsigned short* Bb = m0 + ((wave << 5) + (quad >> 1)) * 512
                                    + l15 * 16 + (quad & 1) * 8;
      bf16x8 b0s[16], b1s[16];
#pragma unroll
      for (int s = 0; s < 16; ++s) {
        b0s[s] = *(const bf16x8*)(Bb + s * 1024);
        b1s[s] = *(const bf16x8*)(Bb + s * 1024 + 256);
      }
      __builtin_amdgcn_sched_barrier(0);   // keep all loads issued first
#pragma unroll
      for (int s = 0; s < 16; ++s) {
        acc0 = __builtin_amdgcn_mfma_f32_16x16x32_bf16(areg[s], b0s[s], acc0, 0, 0, 0);
        acc1 = __builtin_amdgcn_mfma_f32_16x16x32_bf16(areg[s], b1s[s], acc1, 0, 0, 0);
      }
    }
#pragma unroll
    for (int r = 0; r < 4; ++r) {
      red[(wave * 16 + quad * 4 + r) * 33 + l15]      = acc0[r];
      red[(wave * 16 + quad * 4 + r) * 33 + 16 + l15] = acc1[r];
    }
    __syncthreads();                       // barrier #2: red complete

    // ---- phase B: one-pass reduce 8 partials -> inp bf16 ----
    {
      int m = tid >> 5, n = tid & 31;
      float s = 0.f;
#pragma unroll
      for (int w = 0; w < 8; ++w) s += red[(w * 16 + m) * 33 + n];
      inpB[m * 48 + n] = f2bf(s);
    }
    __syncthreads();                       // barrier #3: inpB complete

    // ---- phase C: gates(16x128) = inp@Wih^T + h@Whh^T + b ----
    {
      bf16x8 aI = *(const bf16x8*)(inpB + l15 * 48 + quad * 8);
      bf16x8 aH = *(const bf16x8*)(hB   + l15 * 48 + quad * 8);
      fx4 gacc = {0.f, 0.f, 0.f, 0.f};
      gacc = __builtin_amdgcn_mfma_f32_16x16x32_bf16(aI, bI, gacc, 0, 0, 0);
      gacc = __builtin_amdgcn_mfma_f32_16x16x32_bf16(aH, bH, gacc, 0, 0, 0);
#pragma unroll
      for (int r = 0; r < 4; ++r) gatesLds[(quad * 4 + r) * 132 + g] = gacc[r] + bias;
    }
    __syncthreads();                       // barrier #4: gates complete

    // ---- phase D: LSTM cell elementwise (fp32 state in LDS) ----
    {
      int r = tid >> 5, k = tid & 31;
      float gi = gatesLds[r * 132 + k];
      float gf = gatesLds[r * 132 + 32 + k];
      float gg = gatesLds[r * 132 + 64 + k];
      float go = gatesLds[r * 132 + 96 + k];
      float i_ = 1.f / (1.f + __expf(-gi));
      float f_ = 1.f / (1.f + __expf(-gf));
      float g_ = tanhf(gg);
      float o_ = 1.f / (1.f + __expf(-go));
      float cn = f_ * cB[r * 32 + k] + i_ * g_;
      float hn = o_ * tanhf(cn);
      cB[r * 32 + k] = cn;
      hB[r * 48 + k]  = f2bf(hn);          // next step's h fragment
      cnB[r * 48 + k] = f2bf(cn);
      if (t == ROLLS - 1) gatesLds[r * 132 + k] = hn * Wfc[k];
    }
    __syncthreads();                       // barrier #5: h/c tiles complete

    // ---- phase E + publish (waves 0,1): M_next from registers, 8 B/lane
    // full-line-coverage store, own drain, own PLAIN flag store. Waves
    // 2-7 fall straight through to the next wait_all2 syncthreads. ----
    if (t < ROLLS - 1 && wave < 2) {
      bf16x8 aHn = *(const bf16x8*)(hB  + l15 * 48 + quad * 8);
      bf16x8 aCn = *(const bf16x8*)(cnB + l15 * 48 + quad * 8);
      fx4 m4 = {0.f, 0.f, 0.f, 0.f};
      m4 = __builtin_amdgcn_mfma_f32_16x16x32_bf16(aHn, bWh, m4, 0, 0, 0);
      m4 = __builtin_amdgcn_mfma_f32_16x16x32_bf16(aCn, bWc, m4, 0, 0, 0);
      unsigned short us[4];
#pragma unroll
      for (int r = 0; r < 4; ++r) {
        float xs = m4[r];
#pragma unroll
        for (int f = 0; f < F_INPUT; ++f)
          xs += xLds[(quad * 4 + r) * 8 + f] * wx5[f];
        us[r] = f2bf(xs);
      }
      unsigned long long v = (unsigned long long)(us[0] | ((unsigned)us[1] << 16))
                           | ((unsigned long long)(us[2] | ((unsigned)us[3] << 16)) << 32);
      char* slot = (char*)(m1 + (size_t)bid * 512);
      __hip_atomic_store((unsigned long long*)(slot + g * 32 + quad * 8), v,
                         __ATOMIC_RELAXED, __HIP_MEMORY_SCOPE_AGENT);
      asm volatile("s_waitcnt vmcnt(0)" ::: "memory");
      if (lane == 0)
        __hip_atomic_store(wave ? &flagsB[bid] : &flagsA[bid],
                           (unsigned)(t + 2), __ATOMIC_RELAXED,
                           __HIP_MEMORY_SCOPE_AGENT);
    }
  }

  // ---- epilogue: out = h_final @ Wfc^T + b_fc ----
  __syncthreads();
  if (tid < 16) {
    float s = b_fc[0];
#pragma unroll
    for (int k = 0; k < 32; ++k) s += gatesLds[tid * 132 + k];
    out[row0 + tid] = s;
  }
}

extern "C" void kernel_launch(void* const* d_in, const int* in_sizes, int n_in,
                              void* d_out, int out_size, void* d_ws, size_t ws_size,
                              hipStream_t stream) {
  (void)in_sizes; (void)n_in; (void)out_size; (void)ws_size;
  const float* X   = (const float*)d_in[0];
  const float* A   = (const float*)d_in[1];
  const float* Wx  = (const float*)d_in[2];
  const float* Wh  = (const float*)d_in[3];
  const float* Wc  = (const float*)d_in[4];
  const float* Wih = (const float*)d_in[5];
  const float* Whh = (const float*)d_in[6];
  const float* bih = (const float*)d_in[7];
  const float* bhh = (const float*)d_in[8];
  const float* Wfc = (const float*)d_in[9];
  const float* bfc = (const float*)d_in[10];
  float* outp = (float*)d_out;

  char* ws = (char*)d_ws;
  unsigned short* bufs = (unsigned short*)ws;
  ws += (size_t)NBUF * MT_ELEMS * 2;           // 16 MiB Mt ring
  unsigned* flagsA = (unsigned*)ws; ws += NBLK * sizeof(unsigned);
  unsigned* flagsB = (unsigned*)ws; ws += NBLK * sizeof(unsigned);

  // epoch flags must start at 0 every call (graph-capturable async memset)
  (void)hipMemsetAsync(flagsA, 0, 2 * NBLK * sizeof(unsigned), stream);

  void* args[] = {
    (void*)&A, (void*)&X, (void*)&Wx, (void*)&Wh, (void*)&Wc,
    (void*)&Wih, (void*)&Whh, (void*)&bih, (void*)&bhh,
    (void*)&Wfc, (void*)&bfc, (void*)&outp,
    (void*)&bufs, (void*)&flagsA, (void*)&flagsB
  };
  (void)hipLaunchCooperativeKernel((const void*)k_roll, dim3(NBLK), dim3(512),
                                   args, 0, stream);
}

// Round 15
// 1655.718 us; speedup vs baseline: 1.2693x; 1.0077x over previous
//
#include <hip/hip_runtime.h>

#define N_NODES 4096
#define H_DIM 32
#define F_INPUT 5
#define ROLLS 200
#define NBLK 256
#define NBUF 64                          // Mt ring: write-once per 64 steps
#define MT_ELEMS ((size_t)H_DIM * N_NODES)   // 131072 shorts = 256 KiB

typedef __attribute__((ext_vector_type(8))) short bf16x8;
typedef __attribute__((ext_vector_type(4))) float fx4;

__device__ __forceinline__ unsigned short f2bf(float f) {
  unsigned int u = __builtin_bit_cast(unsigned int, f);
  u += 0x7fffu + ((u >> 16) & 1u);   // round-to-nearest-even (inputs are benign, no NaN/inf)
  return (unsigned short)(u >> 16);
}

// Grid-wait with publisher/poller decoupling: wave 2 (a NON-publisher)
// polls the other 255 blocks' flags while waves 0,1 are still draining
// their publish stores — publish latency overlaps detect latency.
// OWN flags are excluded: own-data visibility is guaranteed by the
// syncthreads (waves 0,1 executed vmcnt(0) before arriving), so no thread
// passes the barrier before own Mt is drained. No atomic RMW anywhere.
__device__ __forceinline__ void wait_grid(const unsigned* fA,
                                          const unsigned* fB, int tid,
                                          int bid, unsigned target) {
  if ((tid >> 6) == 2) {
    int l = tid & 63;
    for (;;) {
      bool ok = true;
#pragma unroll
      for (int j = 0; j < 4; ++j) {
        int blk = l * 4 + j;
        unsigned a = __hip_atomic_load(&fA[blk], __ATOMIC_RELAXED,
                                       __HIP_MEMORY_SCOPE_AGENT);
        unsigned b = __hip_atomic_load(&fB[blk], __ATOMIC_RELAXED,
                                       __HIP_MEMORY_SCOPE_AGENT);
        ok = ok && ((blk == bid) || (a >= target && b >= target));
      }
      if (__ballot(ok) == ~0ull) break;
      __builtin_amdgcn_s_sleep(1);
    }
  }
  __syncthreads();
  asm volatile("" ::: "memory");   // keep Mt loads below the wait
}

// Persistent cooperative kernel (r14 structure + wave-2 poller).
// grid = 256 blocks (1/CU), 512 threads (8 waves), 16 rows/block. A in
// VGPRs; h/c in LDS; Mt ring (64) in global, block-major slot layout
// (shorts): slot[bid*512 + h*16 + row].
// Publish: waves 0,1 each store their M_next half direct from registers
// (full-line coverage), drain own vmcnt, then PLAIN-store their own flag
// array. No post-E barrier; wave 2 is already polling the other blocks.
__global__ __launch_bounds__(512, 2) void k_roll(
    const float* __restrict__ A, const float* __restrict__ X,
    const float* __restrict__ Wx, const float* __restrict__ Wh, const float* __restrict__ Wc,
    const float* __restrict__ Wih, const float* __restrict__ Whh,
    const float* __restrict__ b_ih, const float* __restrict__ b_hh,
    const float* __restrict__ Wfc, const float* __restrict__ b_fc,
    float* __restrict__ out,
    unsigned short* __restrict__ bufs, unsigned* __restrict__ flagsA,
    unsigned* __restrict__ flagsB) {

  __shared__ __align__(16) float red[8 * 16 * 33];          // split-K partials (pad 33)
  __shared__ __align__(16) unsigned short inpB[16 * 48];    // inp bf16, A-frag layout
  __shared__ __align__(16) unsigned short hB[16 * 48];      // persistent h (bf16 frag)
  __shared__ __align__(16) unsigned short cnB[16 * 48];     // c_new bf16 (for M_next)
  __shared__ __align__(16) float cB[16 * 32];               // persistent c (fp32)
  __shared__ __align__(16) float gatesLds[16 * 132];
  __shared__ __align__(16) float xLds[16 * 8];

  const int tid  = threadIdx.x;
  const int wave = tid >> 6;        // 0..7
  const int lane = tid & 63;
  const int l15  = lane & 15;
  const int quad = lane >> 4;       // 0..3
  const int bid  = blockIdx.x;
  const int row0 = bid << 4;

  // ---- prologue: A fragments fp32->bf16 into VGPRs (once) ----
  bf16x8 areg[16];
  {
    const float* Ap = A + (size_t)(row0 + l15) * N_NODES + wave * 512 + quad * 8;
#pragma unroll
    for (int kk = 0; kk < 16; ++kk) {
      bf16x8 a;
#pragma unroll
      for (int j = 0; j < 8; ++j) a[j] = (short)f2bf(Ap[kk * 32 + j]);
      areg[kk] = a;
    }
  }

  // gate weight fragments: wave w owns gate cols [16w, 16w+16)
  const int g = (wave << 4) + l15;
  bf16x8 bI, bH;
#pragma unroll
  for (int j = 0; j < 8; ++j) {
    bI[j] = (short)f2bf(Wih[g * 32 + quad * 8 + j]);
    bH[j] = (short)f2bf(Whh[g * 32 + quad * 8 + j]);
  }
  const float bias = b_ih[g] + b_hh[g];

  // M_next weight fragments (waves 0,1 only): WhT[n][k]=Wh[k][n]; n = g
  bf16x8 bWh, bWc;
  float wx5[F_INPUT];
  if (wave < 2) {
#pragma unroll
    for (int j = 0; j < 8; ++j) {
      bWh[j] = (short)f2bf(Wh[(quad * 8 + j) * H_DIM + g]);
      bWc[j] = (short)f2bf(Wc[(quad * 8 + j) * H_DIM + g]);
    }
#pragma unroll
    for (int f = 0; f < F_INPUT; ++f) wx5[f] = Wx[f * H_DIM + g];
  }

  // h = c = 0 ; Mt0 = (x0 @ Wx)^T staged as floats in gatesLds
  {
    int r = tid >> 5, k = tid & 31;
    hB[r * 48 + k] = 0;       // f2bf(0)==0
    cB[r * 32 + k] = 0.f;
    float s = 0.f;
#pragma unroll
    for (int f = 0; f < F_INPUT; ++f)
      s += X[(size_t)(row0 + r) * F_INPUT + f] * Wx[f * H_DIM + k];
    gatesLds[r * 132 + k] = s;
  }
  __syncthreads();
  if (wave < 2) {              // publish Mt0 half per wave + own plain flag
    unsigned short us[4];
#pragma unroll
    for (int r = 0; r < 4; ++r)
      us[r] = f2bf(gatesLds[(quad * 4 + r) * 132 + g]);
    unsigned long long v = (unsigned long long)(us[0] | ((unsigned)us[1] << 16))
                         | ((unsigned long long)(us[2] | ((unsigned)us[3] << 16)) << 32);
    char* slot = (char*)(bufs + (size_t)bid * 512);
    __hip_atomic_store((unsigned long long*)(slot + g * 32 + quad * 8), v,
                       __ATOMIC_RELAXED, __HIP_MEMORY_SCOPE_AGENT);
    asm volatile("s_waitcnt vmcnt(0)" ::: "memory");
    if (lane == 0)
      __hip_atomic_store(wave ? &flagsB[bid] : &flagsA[bid], 1u,
                         __ATOMIC_RELAXED, __HIP_MEMORY_SCOPE_AGENT);
  }

  for (int t = 0; t < ROLLS; ++t) {
    const unsigned short* m0 = bufs + (size_t)(t & (NBUF - 1)) * MT_ELEMS;
    unsigned short* m1 = bufs + (size_t)((t + 1) & (NBUF - 1)) * MT_ELEMS;

    // ring wrap (t = 0,64,128,192): one L1/L2 tag-invalidate before reuse
    if ((t & (NBUF - 1)) == 0) {
      __syncthreads();
      if (tid < 64)
        __builtin_amdgcn_fence(__ATOMIC_ACQUIRE, "agent");
      __syncthreads();
    }

    // barrier #1: wave 2 polls the other 255 blocks; publishers just join
    wait_grid(flagsA, flagsB, tid, bid, (unsigned)(t + 1));

    // stage x_{t+1} early (waves 0,1 write; same waves read in phase E)
    if (t + 1 < ROLLS && tid < 128) {
      int r = tid >> 3, f = tid & 7;
      if (f < F_INPUT)
        xLds[r * 8 + f] = X[(size_t)(t + 1) * N_NODES * F_INPUT +
                            (size_t)(row0 + r) * F_INPUT + f];
    }

    // ---- phase A: all 32 Mt loads issued first, then MFMA chain ----
    fx4 acc0 = {0.f, 0.f, 0.f, 0.f}, acc1 = {0.f, 0.f, 0.f, 0.f};
    {
      const unsigned short* Bb = m0 + ((wave << 5) + (quad >> 1)) * 512
                                    + l15 * 16 + (quad & 1) * 8;
      bf16x8 b0s[16], b1s[16];
#pragma unroll
      for (int s = 0; s < 16; ++s) {
        b0s[s] = *(const bf16x8*)(Bb + s * 1024);
        b1s[s] = *(const bf16x8*)(Bb + s * 1024 + 256);
      }
      __builtin_amdgcn_sched_barrier(0);   // keep all loads issued first
#pragma unroll
      for (int s = 0; s < 16; ++s) {
        acc0 = __builtin_amdgcn_mfma_f32_16x16x32_bf16(areg[s], b0s[s], acc0, 0, 0, 0);
        acc1 = __builtin_amdgcn_mfma_f32_16x16x32_bf16(areg[s], b1s[s], acc1, 0, 0, 0);
      }
    }
#pragma unroll
    for (int r = 0; r < 4; ++r) {
      red[(wave * 16 + quad * 4 + r) * 33 + l15]      = acc0[r];
      red[(wave * 16 + quad * 4 + r) * 33 + 16 + l15] = acc1[r];
    }
    __syncthreads();                       // barrier #2: red complete

    // ---- phase B: one-pass reduce 8 partials -> inp bf16 ----
    {
      int m = tid >> 5, n = tid & 31;
      float s = 0.f;
#pragma unroll
      for (int w = 0; w < 8; ++w) s += red[(w * 16 + m) * 33 + n];
      inpB[m * 48 + n] = f2bf(s);
    }
    __syncthreads();                       // barrier #3: inpB complete

    // ---- phase C: gates(16x128) = inp@Wih^T + h@Whh^T + b ----
    {
      bf16x8 aI = *(const bf16x8*)(inpB + l15 * 48 + quad * 8);
      bf16x8 aH = *(const bf16x8*)(hB   + l15 * 48 + quad * 8);
      fx4 gacc = {0.f, 0.f, 0.f, 0.f};
      gacc = __builtin_amdgcn_mfma_f32_16x16x32_bf16(aI, bI, gacc, 0, 0, 0);
      gacc = __builtin_amdgcn_mfma_f32_16x16x32_bf16(aH, bH, gacc, 0, 0, 0);
#pragma unroll
      for (int r = 0; r < 4; ++r) gatesLds[(quad * 4 + r) * 132 + g] = gacc[r] + bias;
    }
    __syncthreads();                       // barrier #4: gates complete

    // ---- phase D: LSTM cell elementwise (fp32 state in LDS) ----
    {
      int r = tid >> 5, k = tid & 31;
      float gi = gatesLds[r * 132 + k];
      float gf = gatesLds[r * 132 + 32 + k];
      float gg = gatesLds[r * 132 + 64 + k];
      float go = gatesLds[r * 132 + 96 + k];
      float i_ = 1.f / (1.f + __expf(-gi));
      float f_ = 1.f / (1.f + __expf(-gf));
      float g_ = tanhf(gg);
      float o_ = 1.f / (1.f + __expf(-go));
      float cn = f_ * cB[r * 32 + k] + i_ * g_;
      float hn = o_ * tanhf(cn);
      cB[r * 32 + k] = cn;
      hB[r * 48 + k]  = f2bf(hn);          // next step's h fragment
      cnB[r * 48 + k] = f2bf(cn);
      if (t == ROLLS - 1) gatesLds[r * 132 + k] = hn * Wfc[k];
    }
    __syncthreads();                       // barrier #5: h/c tiles complete

    // ---- phase E + publish (waves 0,1): M_next from registers, 8 B/lane
    // full-line-coverage store, own drain, own PLAIN flag store. Waves
    // 2-7 fall straight through; wave 2 starts polling immediately. ----
    if (t < ROLLS - 1 && wave < 2) {
      bf16x8 aHn = *(const bf16x8*)(hB  + l15 * 48 + quad * 8);
      bf16x8 aCn = *(const bf16x8*)(cnB + l15 * 48 + quad * 8);
      fx4 m4 = {0.f, 0.f, 0.f, 0.f};
      m4 = __builtin_amdgcn_mfma_f32_16x16x32_bf16(aHn, bWh, m4, 0, 0, 0);
      m4 = __builtin_amdgcn_mfma_f32_16x16x32_bf16(aCn, bWc, m4, 0, 0, 0);
      unsigned short us[4];
#pragma unroll
      for (int r = 0; r < 4; ++r) {
        float xs = m4[r];
#pragma unroll
        for (int f = 0; f < F_INPUT; ++f)
          xs += xLds[(quad * 4 + r) * 8 + f] * wx5[f];
        us[r] = f2bf(xs);
      }
      unsigned long long v = (unsigned long long)(us[0] | ((unsigned)us[1] << 16))
                           | ((unsigned long long)(us[2] | ((unsigned)us[3] << 16)) << 32);
      char* slot = (char*)(m1 + (size_t)bid * 512);
      __hip_atomic_store((unsigned long long*)(slot + g * 32 + quad * 8), v,
                         __ATOMIC_RELAXED, __HIP_MEMORY_SCOPE_AGENT);
      asm volatile("s_waitcnt vmcnt(0)" ::: "memory");
      if (lane == 0)
        __hip_atomic_store(wave ? &flagsB[bid] : &flagsA[bid],
                           (unsigned)(t + 2), __ATOMIC_RELAXED,
                           __HIP_MEMORY_SCOPE_AGENT);
    }
  }

  // ---- epilogue: out = h_final @ Wfc^T + b_fc ----
  __syncthreads();
  if (tid < 16) {
    float s = b_fc[0];
#pragma unroll
    for (int k = 0; k < 32; ++k) s += gatesLds[tid * 132 + k];
    out[row0 + tid] = s;
  }
}

extern "C" void kernel_launch(void* const* d_in, const int* in_sizes, int n_in,
                              void* d_out, int out_size, void* d_ws, size_t ws_size,
                              hipStream_t stream) {
  (void)in_sizes; (void)n_in; (void)out_size; (void)ws_size;
  const float* X   = (const float*)d_in[0];
  const float* A   = (const float*)d_in[1];
  const float* Wx  = (const float*)d_in[2];
  const float* Wh  = (const float*)d_in[3];
  const float* Wc  = (const float*)d_in[4];
  const float* Wih = (const float*)d_in[5];
  const float* Whh = (const float*)d_in[6];
  const float* bih = (const float*)d_in[7];
  const float* bhh = (const float*)d_in[8];
  const float* Wfc = (const float*)d_in[9];
  const float* bfc = (const float*)d_in[10];
  float* outp = (float*)d_out;

  char* ws = (char*)d_ws;
  unsigned short* bufs = (unsigned short*)ws;
  ws += (size_t)NBUF * MT_ELEMS * 2;           // 16 MiB Mt ring
  unsigned* flagsA = (unsigned*)ws; ws += NBLK * sizeof(unsigned);
  unsigned* flagsB = (unsigned*)ws; ws += NBLK * sizeof(unsigned);

  // epoch flags must start at 0 every call (graph-capturable async memset)
  (void)hipMemsetAsync(flagsA, 0, 2 * NBLK * sizeof(unsigned), stream);

  void* args[] = {
    (void*)&A, (void*)&X, (void*)&Wx, (void*)&Wh, (void*)&Wc,
    (void*)&Wih, (void*)&Whh, (void*)&bih, (void*)&bhh,
    (void*)&Wfc, (void*)&bfc, (void*)&outp,
    (void*)&bufs, (void*)&flagsA, (void*)&flagsB
  };
  (void)hipLaunchCooperativeKernel((const void*)k_roll, dim3(NBLK), dim3(512),
                                   args, 0, stream);
}